// Round 5
// baseline (6632.219 us; speedup 1.0000x reference)
//
#include <hip/hip_runtime.h>
#include <hip/hip_bf16.h>

#define NBLK 64
#define NTHR 256

typedef __attribute__((ext_vector_type(8))) short short8;
typedef __attribute__((ext_vector_type(4))) float f32x4;
typedef unsigned long long u64;

constexpr int B = 32, T = 512, D = 1024;
constexpr int JW = D / NBLK;           // 16 h-columns per block
constexpr int KW = D / 4;              // 256 K-elements per wave
constexpr int DW = D / 2;              // 512 u64 words per batch row
static_assert(JW * NBLK == D, "partition");

__device__ __forceinline__ unsigned short f2bf(float f) {
  unsigned u = __builtin_bit_cast(unsigned, f);
  u += 0x7FFFu + ((u >> 16) & 1u);     // RNE
  return (unsigned short)(u >> 16);
}

__device__ __forceinline__ float sigm(float v) {
  return 1.0f / (1.0f + __expf(-v));
}

__device__ __forceinline__ float tanh_fast(float v) {
  v = fminf(fmaxf(v, -30.0f), 30.0f);
  float e = __expf(2.0f * v);
  return (e - 1.0f) / (e + 1.0f);
}

// agent-scope relaxed 8B atomics: tag+data travel together, single-copy atomic.
// No fences, no drains, no flags anywhere in the step protocol.
__device__ __forceinline__ void st_u64_llc(u64* p, u64 v) {
  __hip_atomic_store(p, v, __ATOMIC_RELAXED, __HIP_MEMORY_SCOPE_AGENT);
}
__device__ __forceinline__ u64 ld_u64_llc(const u64* p) {
  return __hip_atomic_load(p, __ATOMIC_RELAXED, __HIP_MEMORY_SCOPE_AGENT);
}

struct u32x4s { unsigned x, y, z, w; };

__global__ void __launch_bounds__(NTHR, 1) lstm_persistent(
    const float* __restrict__ x,
    const float* __restrict__ W1, const float* __restrict__ b1,
    const float* __restrict__ W2, const float* __restrict__ b2,
    const float* __restrict__ W3, const float* __restrict__ b3,
    const float* __restrict__ W4, const float* __restrict__ b4,
    const float* __restrict__ bias,
    float* __restrict__ out,            // [B,T,D] ++ cT [B,D] ++ hT [B,D]
    u64* __restrict__ sq)               // [2][B][DW] tagged words
{
  __shared__ float zx[4][B][66];

  const int blk  = blockIdx.x;
  const int tid  = threadIdx.x;
  const int wave = tid >> 6;
  const int lane = tid & 63;
  const int j0   = blk * JW;

  const int col   = lane & 15;          // A-row m (and +16 for second tile)
  const int kg    = (lane >> 4) * 8;    // k sub-offset within a K=32 step
  const int kbase = wave * KW;

  // ---- one-time: weights for all 4 gates over this wave's K slice ----
  const float* Wg[4] = {W1, W2, W3, W4};
  short8 bfrag[4][8];
#pragma unroll
  for (int g = 0; g < 4; ++g) {
    const float* wrow = Wg[g] + (size_t)(j0 + col) * D + kbase;
#pragma unroll
    for (int kk = 0; kk < 8; ++kk) {
      float4 fa = *(const float4*)(wrow + kk * 32 + kg);
      float4 fb = *(const float4*)(wrow + kk * 32 + kg + 4);
      short8 v;
      v[0] = (short)f2bf(fa.x); v[1] = (short)f2bf(fa.y);
      v[2] = (short)f2bf(fa.z); v[3] = (short)f2bf(fa.w);
      v[4] = (short)f2bf(fb.x); v[5] = (short)f2bf(fb.y);
      v[6] = (short)f2bf(fb.z); v[7] = (short)f2bf(fb.w);
      bfrag[g][kk] = v;
    }
  }

  // ---- gate-math thread mapping: batch row gb, h-columns (jp, jp+1) ----
  const int gb   = tid >> 3;            // 0..31
  const int jp   = (tid & 7) * 2;       // 0,2,..,14
  const int jcol = j0 + jp;

  const float bsum0 = bias[jcol], bsum1 = bias[jcol + 1];
  const float bf0 = b1[jcol] + bsum0, bf1 = b1[jcol + 1] + bsum1;
  const float bi0 = b2[jcol] + bsum0, bi1 = b2[jcol + 1] + bsum1;
  const float bg0 = b3[jcol] + bsum0, bg1 = b3[jcol + 1] + bsum1;
  const float bo0 = b4[jcol] + bsum0, bo1 = b4[jcol + 1] + bsum1;

  // ---- publish s_0 = x[:,0,:] slice, tag 1, slot 0 (fire and forget) ----
  {
    float2 x0 = *(const float2*)(x + (size_t)gb * T * D + jcol);
    unsigned d = (unsigned)f2bf(x0.x) | ((unsigned)f2bf(x0.y) << 16);
    st_u64_llc(sq + (size_t)gb * DW + (jcol >> 1), (1ull << 32) | d);
  }

  float c0 = 0.0f, c1 = 0.0f;

  for (int t = 0; t < T; ++t) {
    // x[t+1] prefetch (normal cached, overlaps the poll)
    float xa = 0.0f, xb = 0.0f;
    if (t + 1 < T) {
      float2 xn = *(const float2*)(x + (size_t)gb * T * D + (size_t)(t + 1) * D + jcol);
      xa = xn.x; xb = xn.y;
    }

    // ---- poll this wave's A-fragment words; tag==t+1 validates each word ----
    const unsigned tgt = (unsigned)(t + 1);
    const u64* pa = sq + (size_t)(t & 1) * B * DW + (size_t)col * DW + ((kbase + kg) >> 1);
    const u64* pb = pa + (size_t)16 * DW;
    u64 ua[32], ub[32];
    int guard = 0;
    for (;;) {
#pragma unroll
      for (int kk = 0; kk < 8; ++kk) {
#pragma unroll
        for (int i = 0; i < 4; ++i) {
          ua[kk * 4 + i] = ld_u64_llc(pa + kk * 16 + i);
          ub[kk * 4 + i] = ld_u64_llc(pb + kk * 16 + i);
        }
      }
      unsigned ok = 1u;
#pragma unroll
      for (int i = 0; i < 32; ++i) {
        ok &= (unsigned)(ua[i] >> 32) == tgt;
        ok &= (unsigned)(ub[i] >> 32) == tgt;
      }
      if (__all((int)ok)) break;
      if (++guard > (1 << 16)) break;   // fail loud (absmax), never hang
    }
    __builtin_amdgcn_sched_barrier(0);

    // ---- pack low dwords -> bf16 fragments; MFMA M=32 x N=64 x K=256 ----
    f32x4 acc[2][4];
#pragma unroll
    for (int mt = 0; mt < 2; ++mt)
#pragma unroll
      for (int g = 0; g < 4; ++g) acc[mt][g] = (f32x4){0.f, 0.f, 0.f, 0.f};

#pragma unroll
    for (int kk = 0; kk < 8; ++kk) {
      u32x4s q0 = {(unsigned)ua[4 * kk], (unsigned)ua[4 * kk + 1],
                   (unsigned)ua[4 * kk + 2], (unsigned)ua[4 * kk + 3]};
      u32x4s q1 = {(unsigned)ub[4 * kk], (unsigned)ub[4 * kk + 1],
                   (unsigned)ub[4 * kk + 2], (unsigned)ub[4 * kk + 3]};
      short8 a0 = __builtin_bit_cast(short8, q0);
      short8 a1 = __builtin_bit_cast(short8, q1);
#pragma unroll
      for (int g = 0; g < 4; ++g) {
        acc[0][g] = __builtin_amdgcn_mfma_f32_16x16x32_bf16(a0, bfrag[g][kk], acc[0][g], 0, 0, 0);
        acc[1][g] = __builtin_amdgcn_mfma_f32_16x16x32_bf16(a1, bfrag[g][kk], acc[1][g], 0, 0, 0);
      }
    }

    // ---- exchange partials (C/D layout: n=lane&15, m=(lane>>4)*4+r) ----
    {
      const int zr = (lane >> 4) * 4;
#pragma unroll
      for (int g = 0; g < 4; ++g)
#pragma unroll
        for (int r = 0; r < 4; ++r) {
          zx[wave][zr + r][g * 16 + col]      = acc[0][g][r];
          zx[wave][zr + r + 16][g * 16 + col] = acc[1][g][r];
        }
    }
    __syncthreads();

    // ---- reduce 4 K-partials + gate math ----
    float zf0, zf1, zi0, zi1, zg0, zg1, zo0, zo1;
    {
      float2 f_ = *(const float2*)&zx[0][gb][jp];
      float2 i_ = *(const float2*)&zx[0][gb][16 + jp];
      float2 g_ = *(const float2*)&zx[0][gb][32 + jp];
      float2 o_ = *(const float2*)&zx[0][gb][48 + jp];
      zf0 = f_.x; zf1 = f_.y; zi0 = i_.x; zi1 = i_.y;
      zg0 = g_.x; zg1 = g_.y; zo0 = o_.x; zo1 = o_.y;
#pragma unroll
      for (int w = 1; w < 4; ++w) {
        f_ = *(const float2*)&zx[w][gb][jp];
        i_ = *(const float2*)&zx[w][gb][16 + jp];
        g_ = *(const float2*)&zx[w][gb][32 + jp];
        o_ = *(const float2*)&zx[w][gb][48 + jp];
        zf0 += f_.x; zf1 += f_.y; zi0 += i_.x; zi1 += i_.y;
        zg0 += g_.x; zg1 += g_.y; zo0 += o_.x; zo1 += o_.y;
      }
    }

    float f0 = sigm(zf0 + bf0), f1 = sigm(zf1 + bf1);
    float i0 = sigm(zi0 + bi0) * tanh_fast(zg0 + bg0);
    float i1 = sigm(zi1 + bi1) * tanh_fast(zg1 + bg1);
    c0 = c0 * f0 + i0;
    c1 = c1 * f1 + i1;
    float h0 = sigm(zo0 + bo0) * tanh_fast(c0);
    float h1 = sigm(zo1 + bo1) * tanh_fast(c1);

    if (t + 1 < T) {
      // publish s_{t+1}: ONE tagged 8B store, fire-and-forget
      u64* snq = sq + (size_t)((t + 1) & 1) * B * DW;
      unsigned d = (unsigned)f2bf(h0 + xa) | ((unsigned)f2bf(h1 + xb) << 16);
      st_u64_llc(snq + (size_t)gb * DW + (jcol >> 1), ((u64)(t + 2) << 32) | d);
      __syncthreads();   // zx reuse guard (after publish, off critical path)
      *(float2*)(out + (size_t)gb * T * D + (size_t)t * D + jcol) = make_float2(h0, h1);
    } else {
      *(float2*)(out + (size_t)gb * T * D + (size_t)t * D + jcol) = make_float2(h0, h1);
      float* cT = out + (size_t)B * T * D;
      float* hT = cT + (size_t)B * D;
      *(float2*)(cT + (size_t)gb * D + jcol) = make_float2(c0, c1);
      *(float2*)(hT + (size_t)gb * D + jcol) = make_float2(h0, h1);
    }
  }
}

extern "C" void kernel_launch(void* const* d_in, const int* in_sizes, int n_in,
                              void* d_out, int out_size, void* d_ws, size_t ws_size,
                              hipStream_t stream) {
  const float* x    = (const float*)d_in[0];
  const float* W1   = (const float*)d_in[1];
  const float* b1   = (const float*)d_in[2];
  const float* W2   = (const float*)d_in[3];
  const float* b2   = (const float*)d_in[4];
  const float* W3   = (const float*)d_in[5];
  const float* b3   = (const float*)d_in[6];
  const float* W4   = (const float*)d_in[7];
  const float* b4   = (const float*)d_in[8];
  const float* bias = (const float*)d_in[9];

  u64* sq = (u64*)d_ws;   // [2][B][DW] tagged words = 256 KB

  // zero tags (tag 0 matches no target 1..T+1); cheap insurance for first call
  hipMemsetAsync(d_ws, 0, (size_t)2 * B * DW * sizeof(u64), stream);
  hipLaunchKernelGGL(lstm_persistent, dim3(NBLK), dim3(NTHR), 0, stream,
                     x, W1, b1, W2, b2, W3, b3, W4, b4, bias,
                     (float*)d_out, sq);
}

// Round 6
// 3286.523 us; speedup vs baseline: 2.0180x; 2.0180x over previous
//
#include <hip/hip_runtime.h>
#include <hip/hip_bf16.h>

#define NBLK 64
#define NTHR 256

typedef __attribute__((ext_vector_type(8))) short short8;
typedef __attribute__((ext_vector_type(4))) float f32x4;
typedef unsigned long long u64;

constexpr int B = 32, T = 512, D = 1024;
constexpr int JW = D / NBLK;           // 16 h-columns per block
constexpr int KW = D / 4;              // 256 K-elements per wave (consumer role)
static_assert(JW * NBLK == D, "partition");

__device__ __forceinline__ unsigned short f2bf(float f) {
  unsigned u = __builtin_bit_cast(unsigned, f);
  u += 0x7FFFu + ((u >> 16) & 1u);     // RNE
  return (unsigned short)(u >> 16);
}

__device__ __forceinline__ float sigm(float v) {
  return 1.0f / (1.0f + __expf(-v));
}

__device__ __forceinline__ float tanh_fast(float v) {
  v = fminf(fmaxf(v, -30.0f), 30.0f);
  float e = __expf(2.0f * v);
  return (e - 1.0f) / (e + 1.0f);
}

// proven coherence path: bypass L1+L2, coherent at LLC (same as rounds 1-2)
__device__ __forceinline__ void st_u32_llc(unsigned* p, unsigned v) {
  asm volatile("global_store_dword %0, %1, off sc0 sc1" :: "v"(p), "v"(v) : "memory");
}
__device__ __forceinline__ unsigned ld_u32_llc(const unsigned* p) {
  return __hip_atomic_load(p, __ATOMIC_RELAXED, __HIP_MEMORY_SCOPE_AGENT);
}

__global__ void __launch_bounds__(NTHR, 1) lstm_persistent(
    const float* __restrict__ x,
    const float* __restrict__ W1, const float* __restrict__ b1,
    const float* __restrict__ W2, const float* __restrict__ b2,
    const float* __restrict__ W3, const float* __restrict__ b3,
    const float* __restrict__ W4, const float* __restrict__ b4,
    const float* __restrict__ bias,
    float* __restrict__ out,            // [B,T,D] ++ cT [B,D] ++ hT [B,D]
    unsigned* __restrict__ flags,       // [256] per-wave step flags, 4B stride
    unsigned short* __restrict__ sbuf)  // [2][B][D] bf16, double-buffered
{
  __shared__ float zx[2][4][B][66];     // parity-double-buffered exchange

  const int blk  = blockIdx.x;
  const int tid  = threadIdx.x;
  const int wv   = tid >> 6;
  const int lane = tid & 63;
  const int j0   = blk * JW;

  // consumer-role mapping (MFMA fragments)
  const int col   = lane & 15;          // A-row m (and +16 for second tile)
  const int kg    = (lane >> 4) * 8;    // k sub-offset within a K=32 step
  const int kbase = wv * KW;

  // ---- one-time: weights for all 4 gates over this wave's K slice ----
  const float* Wg[4] = {W1, W2, W3, W4};
  short8 bfrag[4][8];
#pragma unroll
  for (int g = 0; g < 4; ++g) {
    const float* wrow = Wg[g] + (size_t)(j0 + col) * D + kbase;
#pragma unroll
    for (int kk = 0; kk < 8; ++kk) {
      float4 fa = *(const float4*)(wrow + kk * 32 + kg);
      float4 fb = *(const float4*)(wrow + kk * 32 + kg + 4);
      short8 v;
      v[0] = (short)f2bf(fa.x); v[1] = (short)f2bf(fa.y);
      v[2] = (short)f2bf(fa.z); v[3] = (short)f2bf(fa.w);
      v[4] = (short)f2bf(fb.x); v[5] = (short)f2bf(fb.y);
      v[6] = (short)f2bf(fb.z); v[7] = (short)f2bf(fb.w);
      bfrag[g][kk] = v;
    }
  }

  // producer-role mapping: wave wv owns cols [j0+4wv, j0+4wv+4), all 32 rows
  const int gb   = lane >> 1;           // batch row 0..31
  const int jp   = 4 * wv + 2 * (lane & 1);
  const int jcol = j0 + jp;

  unsigned* myflag      = flags + 4 * blk + wv;    // producer-wave id = jcol>>2
  const unsigned* pollp = flags + 64 * wv + lane;  // 64 consecutive flags

  const float bsum0 = bias[jcol], bsum1 = bias[jcol + 1];
  const float bf0 = b1[jcol] + bsum0, bf1 = b1[jcol + 1] + bsum1;
  const float bi0 = b2[jcol] + bsum0, bi1 = b2[jcol + 1] + bsum1;
  const float bg0 = b3[jcol] + bsum0, bg1 = b3[jcol + 1] + bsum1;
  const float bo0 = b4[jcol] + bsum0, bo1 = b4[jcol + 1] + bsum1;

  // ---- publish s_0 slice (wave-autonomous: store, drain own wave, flag) ----
  {
    float2 x0 = *(const float2*)(x + (size_t)gb * T * D + jcol);
    st_u32_llc((unsigned*)(sbuf + (size_t)gb * D + jcol),
               (unsigned)f2bf(x0.x) | ((unsigned)f2bf(x0.y) << 16));
    asm volatile("s_waitcnt vmcnt(0)" ::: "memory");
    if (lane == 0) st_u32_llc(myflag, 1u);
  }

  float c0 = 0.0f, c1 = 0.0f;

  for (int t = 0; t < T; ++t) {
    // x[t+1] prefetch (plain cached load; completes under poll/MFMA)
    float xa = 0.0f, xb = 0.0f;
    if (t + 1 < T) {
      float2 xn = *(const float2*)(x + (size_t)gb * T * D + (size_t)(t + 1) * D + jcol);
      xa = xn.x; xb = xn.y;
    }

    // ---- tight poll: 64 producer-wave flags in one coalesced 256B burst ----
    {
      const unsigned tgt = (unsigned)(t + 1);
      int guard = 0;
      for (;;) {
        unsigned f = ld_u32_llc(pollp);
        if (__all((int)(f >= tgt))) break;
        if (++guard > (1 << 22)) break;   // fail loud, never hang
      }
    }
    asm volatile("" ::: "memory");
    __builtin_amdgcn_sched_barrier(0);

    // ---- batched A-loads: 16 x dwordx4 sc0 sc1, one pipelined RT ----
    const unsigned short* ap = sbuf + (size_t)(t & 1) * B * D + (size_t)col * D + kbase + kg;
    short8 a0[8], a1[8];
#pragma unroll
    for (int kk = 0; kk < 8; ++kk) {
      asm volatile("global_load_dwordx4 %0, %1, off sc0 sc1"
                   : "=v"(a0[kk]) : "v"(ap + kk * 32));
      asm volatile("global_load_dwordx4 %0, %1, off sc0 sc1"
                   : "=v"(a1[kk]) : "v"(ap + 16 * D + kk * 32));
    }
    asm volatile("s_waitcnt vmcnt(0)" ::: "memory");
    __builtin_amdgcn_sched_barrier(0);

    // ---- z partial: M=32 x N=64 (4 gates x 16) x K=256 ----
    f32x4 acc[2][4];
#pragma unroll
    for (int mt = 0; mt < 2; ++mt)
#pragma unroll
      for (int g = 0; g < 4; ++g) acc[mt][g] = (f32x4){0.f, 0.f, 0.f, 0.f};

#pragma unroll
    for (int kk = 0; kk < 8; ++kk) {
#pragma unroll
      for (int g = 0; g < 4; ++g) {
        acc[0][g] = __builtin_amdgcn_mfma_f32_16x16x32_bf16(a0[kk], bfrag[g][kk], acc[0][g], 0, 0, 0);
        acc[1][g] = __builtin_amdgcn_mfma_f32_16x16x32_bf16(a1[kk], bfrag[g][kk], acc[1][g], 0, 0, 0);
      }
    }

    // ---- exchange partials into parity buffer; ONE barrier per step ----
    {
      const int pz = t & 1;
      const int zr = (lane >> 4) * 4;
#pragma unroll
      for (int g = 0; g < 4; ++g)
#pragma unroll
        for (int r = 0; r < 4; ++r) {
          zx[pz][wv][zr + r][g * 16 + col]      = acc[0][g][r];
          zx[pz][wv][zr + r + 16][g * 16 + col] = acc[1][g][r];
        }
    }
    __syncthreads();

    // ---- reduce 4 K-partials + gate math for (gb, jcol/jcol+1) ----
    const int pz = t & 1;
    float zf0, zf1, zi0, zi1, zg0, zg1, zo0, zo1;
    {
      float2 f_ = *(const float2*)&zx[pz][0][gb][jp];
      float2 i_ = *(const float2*)&zx[pz][0][gb][16 + jp];
      float2 g_ = *(const float2*)&zx[pz][0][gb][32 + jp];
      float2 o_ = *(const float2*)&zx[pz][0][gb][48 + jp];
      zf0 = f_.x; zf1 = f_.y; zi0 = i_.x; zi1 = i_.y;
      zg0 = g_.x; zg1 = g_.y; zo0 = o_.x; zo1 = o_.y;
#pragma unroll
      for (int w = 1; w < 4; ++w) {
        f_ = *(const float2*)&zx[pz][w][gb][jp];
        i_ = *(const float2*)&zx[pz][w][gb][16 + jp];
        g_ = *(const float2*)&zx[pz][w][gb][32 + jp];
        o_ = *(const float2*)&zx[pz][w][gb][48 + jp];
        zf0 += f_.x; zf1 += f_.y; zi0 += i_.x; zi1 += i_.y;
        zg0 += g_.x; zg1 += g_.y; zo0 += o_.x; zo1 += o_.y;
      }
    }

    float f0 = sigm(zf0 + bf0), f1 = sigm(zf1 + bf1);
    float i0 = sigm(zi0 + bi0) * tanh_fast(zg0 + bg0);
    float i1 = sigm(zi1 + bi1) * tanh_fast(zg1 + bg1);
    c0 = c0 * f0 + i0;
    c1 = c1 * f1 + i1;
    float h0 = sigm(zo0 + bo0) * tanh_fast(c0);
    float h1 = sigm(zo1 + bo1) * tanh_fast(c1);

    if (t + 1 < T) {
      // wave-autonomous publish: store own slab, drain OWN wave, raise flag
      unsigned short* snext = sbuf + (size_t)((t + 1) & 1) * B * D;
      st_u32_llc((unsigned*)(snext + (size_t)gb * D + jcol),
                 (unsigned)f2bf(h0 + xa) | ((unsigned)f2bf(h1 + xb) << 16));
      asm volatile("s_waitcnt vmcnt(0)" ::: "memory");
      if (lane == 0) st_u32_llc(myflag, (unsigned)(t + 2));
      // out store off the critical path (plain cached)
      *(float2*)(out + (size_t)gb * T * D + (size_t)t * D + jcol) = make_float2(h0, h1);
    } else {
      *(float2*)(out + (size_t)gb * T * D + (size_t)t * D + jcol) = make_float2(h0, h1);
      float* cT = out + (size_t)B * T * D;
      float* hT = cT + (size_t)B * D;
      *(float2*)(cT + (size_t)gb * D + jcol) = make_float2(c0, c1);
      *(float2*)(hT + (size_t)gb * D + jcol) = make_float2(h0, h1);
    }
  }
}

extern "C" void kernel_launch(void* const* d_in, const int* in_sizes, int n_in,
                              void* d_out, int out_size, void* d_ws, size_t ws_size,
                              hipStream_t stream) {
  const float* x    = (const float*)d_in[0];
  const float* W1   = (const float*)d_in[1];
  const float* b1   = (const float*)d_in[2];
  const float* W2   = (const float*)d_in[3];
  const float* b2   = (const float*)d_in[4];
  const float* W3   = (const float*)d_in[5];
  const float* b3   = (const float*)d_in[6];
  const float* W4   = (const float*)d_in[7];
  const float* b4   = (const float*)d_in[8];
  const float* bias = (const float*)d_in[9];

  unsigned* flags      = (unsigned*)d_ws;                        // 256 * 4B = 1 KB
  unsigned short* sbuf = (unsigned short*)((char*)d_ws + 4096);  // 2*B*D bf16 = 128 KB

  hipMemsetAsync(d_ws, 0, 4096, stream);  // reset flags every call (replay-safe)
  hipLaunchKernelGGL(lstm_persistent, dim3(NBLK), dim3(NTHR), 0, stream,
                     x, W1, b1, W2, b2, W3, b3, W4, b4, bias,
                     (float*)d_out, flags, sbuf);
}

// Round 7
// 2422.471 us; speedup vs baseline: 2.7378x; 1.3567x over previous
//
#include <hip/hip_runtime.h>
#include <hip/hip_bf16.h>

#define NBLK 64
#define NTHR 256

typedef __attribute__((ext_vector_type(8))) short short8;
typedef __attribute__((ext_vector_type(4))) float f32x4;

constexpr int B = 32, T = 512, D = 1024;
constexpr int JW = D / NBLK;           // 16 h-columns per block (= per tile)
constexpr int KW = D / 4;              // 256 K-elements per wave
static_assert(JW * NBLK == D, "partition");

// s layout (tile-major): u32 sq[2][64 tiles][256]  — tile t holds h-cols
// [16t,16t+16) x 32 rows as [row][colpair]; one tile = 1 KB contiguous,
// written by exactly block t as a thread-linear burst.

__device__ __forceinline__ unsigned short f2bf(float f) {
  unsigned u = __builtin_bit_cast(unsigned, f);
  u += 0x7FFFu + ((u >> 16) & 1u);     // RNE
  return (unsigned short)(u >> 16);
}

__device__ __forceinline__ float sigm(float v) {
  return 1.0f / (1.0f + __expf(-v));
}

__device__ __forceinline__ float tanh_fast(float v) {
  v = fminf(fmaxf(v, -30.0f), 30.0f);
  float e = __expf(2.0f * v);
  return (e - 1.0f) / (e + 1.0f);
}

// proven coherence path (rounds 1-2-6): bypass L1+L2, coherent at LLC
__device__ __forceinline__ void st_u32_llc(unsigned* p, unsigned v) {
  asm volatile("global_store_dword %0, %1, off sc0 sc1" :: "v"(p), "v"(v) : "memory");
}
__device__ __forceinline__ unsigned ld_u32_llc(const unsigned* p) {
  return __hip_atomic_load(p, __ATOMIC_RELAXED, __HIP_MEMORY_SCOPE_AGENT);
}

__global__ void __launch_bounds__(NTHR, 1) lstm_persistent(
    const float* __restrict__ x,
    const float* __restrict__ W1, const float* __restrict__ b1,
    const float* __restrict__ W2, const float* __restrict__ b2,
    const float* __restrict__ W3, const float* __restrict__ b3,
    const float* __restrict__ W4, const float* __restrict__ b4,
    const float* __restrict__ bias,
    float* __restrict__ out,            // [B,T,D] ++ cT [B,D] ++ hT [B,D]
    unsigned* __restrict__ flags,       // [64] dense per-block step flags
    unsigned* __restrict__ sq)          // [2][64][256] u32 tile-major s
{
  __shared__ float zx[4][B][66];

  const int blk  = blockIdx.x;
  const int tid  = threadIdx.x;
  const int wv   = tid >> 6;
  const int lane = tid & 63;
  const int j0   = blk * JW;

  // consumer-role mapping (MFMA fragments)
  const int m     = lane & 15;          // A-row (tile0); +16 for tile1
  const int kg    = (lane >> 4) * 8;    // k sub-offset within a K=32 step
  const int kbase = wv * KW;

  // ---- one-time: weights for all 4 gates over this wave's K slice ----
  const float* Wg[4] = {W1, W2, W3, W4};
  short8 bfrag[4][8];
#pragma unroll
  for (int g = 0; g < 4; ++g) {
    const float* wrow = Wg[g] + (size_t)(j0 + m) * D + kbase;
#pragma unroll
    for (int kk = 0; kk < 8; ++kk) {
      float4 fa = *(const float4*)(wrow + kk * 32 + kg);
      float4 fb = *(const float4*)(wrow + kk * 32 + kg + 4);
      short8 v;
      v[0] = (short)f2bf(fa.x); v[1] = (short)f2bf(fa.y);
      v[2] = (short)f2bf(fa.z); v[3] = (short)f2bf(fa.w);
      v[4] = (short)f2bf(fb.x); v[5] = (short)f2bf(fb.y);
      v[6] = (short)f2bf(fb.z); v[7] = (short)f2bf(fb.w);
      bfrag[g][kk] = v;
    }
  }

  // producer/gate-math mapping: thread tid -> (row gb, colpair jp); publish
  // address is sq[slot][blk][tid] — thread-linear 1 KB burst per block.
  const int gb   = tid >> 3;            // 0..31
  const int jp   = (tid & 7) * 2;      // 0,2,..,14
  const int jcol = j0 + jp;

  const float bsum0 = bias[jcol], bsum1 = bias[jcol + 1];
  const float bf0 = b1[jcol] + bsum0, bf1 = b1[jcol + 1] + bsum1;
  const float bi0 = b2[jcol] + bsum0, bi1 = b2[jcol + 1] + bsum1;
  const float bg0 = b3[jcol] + bsum0, bg1 = b3[jcol + 1] + bsum1;
  const float bo0 = b4[jcol] + bsum0, bo1 = b4[jcol + 1] + bsum1;

  // ---- publish s_0 = x[:,0,:] tile (coalesced), drain, flag ----
  {
    float2 x0 = *(const float2*)(x + (size_t)gb * T * D + jcol);
    st_u32_llc(sq + blk * 256 + tid,
               (unsigned)f2bf(x0.x) | ((unsigned)f2bf(x0.y) << 16));
  }
  asm volatile("s_waitcnt vmcnt(0)" ::: "memory");
  __syncthreads();
  if (tid == 0) st_u32_llc(&flags[blk], 1u);

  // A-load base (u16 units): tile (kbase>>4)+(kg>>4), row m, col (kg&8)
  const int tb0 = (kbase >> 4) + (kg >> 4);
  const int aoff = tb0 * 512 + m * 16 + (kg & 8);

  // consumer poll target: 16 producer flags in ONE 64B line
  const unsigned* pollp = flags + wv * 16 + (lane & 15);

  float c0 = 0.0f, c1 = 0.0f;

  for (int t = 0; t < T; ++t) {
    // x[t+1] prefetch (plain cached; completes under poll/MFMA)
    float xa = 0.0f, xb = 0.0f;
    if (t + 1 < T) {
      float2 xn = *(const float2*)(x + (size_t)gb * T * D + (size_t)(t + 1) * D + jcol);
      xa = xn.x; xb = xn.y;
    }

    // ---- tight poll on one flag line ----
    {
      const unsigned tgt = (unsigned)(t + 1);
      int guard = 0;
      for (;;) {
        unsigned f = ld_u32_llc(pollp);
        if (__all((int)(f >= tgt))) break;
        if (++guard > (1 << 22)) break;   // fail loud, never hang
      }
    }
    asm volatile("" ::: "memory");
    __builtin_amdgcn_sched_barrier(0);

    // ---- batched A-loads from tile-major s: 16 x dwordx4, 256B bursts ----
    const unsigned short* ap =
        (const unsigned short*)sq + (size_t)(t & 1) * 32768 + aoff;
    short8 a0[8], a1[8];
#pragma unroll
    for (int kk = 0; kk < 8; ++kk) {
      asm volatile("global_load_dwordx4 %0, %1, off sc0 sc1"
                   : "=v"(a0[kk]) : "v"(ap + kk * 1024));
      asm volatile("global_load_dwordx4 %0, %1, off sc0 sc1"
                   : "=v"(a1[kk]) : "v"(ap + kk * 1024 + 256));
    }
    asm volatile("s_waitcnt vmcnt(0)" ::: "memory");
    __builtin_amdgcn_sched_barrier(0);

    // ---- z partial: M=32 x N=64 (4 gates x 16) x K=256 ----
    f32x4 acc[2][4];
#pragma unroll
    for (int mt = 0; mt < 2; ++mt)
#pragma unroll
      for (int g = 0; g < 4; ++g) acc[mt][g] = (f32x4){0.f, 0.f, 0.f, 0.f};

#pragma unroll
    for (int kk = 0; kk < 8; ++kk) {
#pragma unroll
      for (int g = 0; g < 4; ++g) {
        acc[0][g] = __builtin_amdgcn_mfma_f32_16x16x32_bf16(a0[kk], bfrag[g][kk], acc[0][g], 0, 0, 0);
        acc[1][g] = __builtin_amdgcn_mfma_f32_16x16x32_bf16(a1[kk], bfrag[g][kk], acc[1][g], 0, 0, 0);
      }
    }

    // ---- exchange partials (C/D layout: n=lane&15, m=(lane>>4)*4+r) ----
    {
      const int zr = (lane >> 4) * 4;
#pragma unroll
      for (int g = 0; g < 4; ++g)
#pragma unroll
        for (int r = 0; r < 4; ++r) {
          zx[wv][zr + r][g * 16 + m]      = acc[0][g][r];
          zx[wv][zr + r + 16][g * 16 + m] = acc[1][g][r];
        }
    }
    __syncthreads();

    // ---- reduce 4 K-partials + gate math for (gb, jcol/jcol+1) ----
    float zf0, zf1, zi0, zi1, zg0, zg1, zo0, zo1;
    {
      float2 f_ = *(const float2*)&zx[0][gb][jp];
      float2 i_ = *(const float2*)&zx[0][gb][16 + jp];
      float2 g_ = *(const float2*)&zx[0][gb][32 + jp];
      float2 o_ = *(const float2*)&zx[0][gb][48 + jp];
      zf0 = f_.x; zf1 = f_.y; zi0 = i_.x; zi1 = i_.y;
      zg0 = g_.x; zg1 = g_.y; zo0 = o_.x; zo1 = o_.y;
#pragma unroll
      for (int w = 1; w < 4; ++w) {
        f_ = *(const float2*)&zx[w][gb][jp];
        i_ = *(const float2*)&zx[w][gb][16 + jp];
        g_ = *(const float2*)&zx[w][gb][32 + jp];
        o_ = *(const float2*)&zx[w][gb][48 + jp];
        zf0 += f_.x; zf1 += f_.y; zi0 += i_.x; zi1 += i_.y;
        zg0 += g_.x; zg1 += g_.y; zo0 += o_.x; zo1 += o_.y;
      }
    }

    float f0 = sigm(zf0 + bf0), f1 = sigm(zf1 + bf1);
    float i0 = sigm(zi0 + bi0) * tanh_fast(zg0 + bg0);
    float i1 = sigm(zi1 + bi1) * tanh_fast(zg1 + bg1);
    c0 = c0 * f0 + i0;
    c1 = c1 * f1 + i1;
    float h0 = sigm(zo0 + bo0) * tanh_fast(c0);
    float h1 = sigm(zo1 + bo1) * tanh_fast(c1);

    if (t + 1 < T) {
      // coalesced publish: block's whole tile = 1 KB thread-linear burst
      unsigned* snq = sq + (size_t)((t + 1) & 1) * 16384 + blk * 256;
      st_u32_llc(snq + tid,
                 (unsigned)f2bf(h0 + xa) | ((unsigned)f2bf(h1 + xb) << 16));
      asm volatile("s_waitcnt vmcnt(0)" ::: "memory");
      __syncthreads();                   // join waves + zx reuse guard
      if (tid == 0) st_u32_llc(&flags[blk], (unsigned)(t + 2));
      // out store off the critical path (plain cached)
      *(float2*)(out + (size_t)gb * T * D + (size_t)t * D + jcol) = make_float2(h0, h1);
    } else {
      *(float2*)(out + (size_t)gb * T * D + (size_t)t * D + jcol) = make_float2(h0, h1);
      float* cT = out + (size_t)B * T * D;
      float* hT = cT + (size_t)B * D;
      *(float2*)(cT + (size_t)gb * D + jcol) = make_float2(c0, c1);
      *(float2*)(hT + (size_t)gb * D + jcol) = make_float2(h0, h1);
    }
  }
}

extern "C" void kernel_launch(void* const* d_in, const int* in_sizes, int n_in,
                              void* d_out, int out_size, void* d_ws, size_t ws_size,
                              hipStream_t stream) {
  const float* x    = (const float*)d_in[0];
  const float* W1   = (const float*)d_in[1];
  const float* b1   = (const float*)d_in[2];
  const float* W2   = (const float*)d_in[3];
  const float* b2   = (const float*)d_in[4];
  const float* W3   = (const float*)d_in[5];
  const float* b3   = (const float*)d_in[6];
  const float* W4   = (const float*)d_in[7];
  const float* b4   = (const float*)d_in[8];
  const float* bias = (const float*)d_in[9];

  unsigned* flags = (unsigned*)d_ws;                     // 64 * 4B dense
  unsigned* sq    = (unsigned*)((char*)d_ws + 1024);     // [2][64][256] u32 = 128 KB

  hipMemsetAsync(d_ws, 0, 1024, stream);  // reset flags every call (replay-safe)
  hipLaunchKernelGGL(lstm_persistent, dim3(NBLK), dim3(NTHR), 0, stream,
                     x, W1, b1, W2, b2, W3, b3, W4, b4, bias,
                     (float*)d_out, flags, sq);
}

// Round 8
// 1786.014 us; speedup vs baseline: 3.7134x; 1.3564x over previous
//
#include <hip/hip_runtime.h>
#include <hip/hip_bf16.h>

#define NBLK 64
#define NTHR 256

typedef __attribute__((ext_vector_type(8))) short short8;
typedef __attribute__((ext_vector_type(4))) float f32x4;

constexpr int B = 32, T = 512, D = 1024;
constexpr int JW = D / NBLK;           // 16 h-columns per block (= per tile)
constexpr int KW = D / 4;              // 256 K-elements per wave
static_assert(JW * NBLK == D, "partition");

// ws layout:
//   0     : flags, 8 replicas x 256 u32 (replica r at r*1024 B); id = 4*blk+wv
//   8192  : sq [2][64][256] u32 tile-major s (tile = 1 KB: [row32][colpair8])

__device__ __forceinline__ unsigned short f2bf(float f) {
  unsigned u = __builtin_bit_cast(unsigned, f);
  u += 0x7FFFu + ((u >> 16) & 1u);     // RNE
  return (unsigned short)(u >> 16);
}

__device__ __forceinline__ float sigm(float v) {
  return 1.0f / (1.0f + __expf(-v));
}

__device__ __forceinline__ float tanh_fast(float v) {
  v = fminf(fmaxf(v, -30.0f), 30.0f);
  float e = __expf(2.0f * v);
  return (e - 1.0f) / (e + 1.0f);
}

// proven coherence path: bypass L1+L2, coherent at LLC
__device__ __forceinline__ void st_u32_llc(unsigned* p, unsigned v) {
  asm volatile("global_store_dword %0, %1, off sc0 sc1" :: "v"(p), "v"(v) : "memory");
}
__device__ __forceinline__ unsigned ld_u32_llc(const unsigned* p) {
  return __hip_atomic_load(p, __ATOMIC_RELAXED, __HIP_MEMORY_SCOPE_AGENT);
}

__global__ void __launch_bounds__(NTHR, 1) lstm_persistent(
    const float* __restrict__ x,
    const float* __restrict__ W1, const float* __restrict__ b1,
    const float* __restrict__ W2, const float* __restrict__ b2,
    const float* __restrict__ W3, const float* __restrict__ b3,
    const float* __restrict__ W4, const float* __restrict__ b4,
    const float* __restrict__ bias,
    float* __restrict__ out,            // [B,T,D] ++ cT [B,D] ++ hT [B,D]
    unsigned* __restrict__ flags,       // 8 replicas x 256 per-wave step flags
    unsigned* __restrict__ sq)          // [2][64][256] u32 tile-major s
{
  __shared__ float zx[2][4][B][72];     // parity-doubled; pad 72 -> 2-way only

  const int blk  = blockIdx.x;
  const int tid  = threadIdx.x;
  const int wv   = tid >> 6;
  const int lane = tid & 63;
  const int j0   = blk * JW;
  const int rot  = blk & 7;             // K-slice rotation (de-burst LLC lines)

  // consumer-role mapping (MFMA fragments)
  const int m     = lane & 15;          // A-row (tile0); +16 for tile1
  const int kg    = (lane >> 4) * 8;    // k sub-offset within a K=32 step
  const int kbase = wv * KW;

  // ---- one-time: weights for all 4 gates over this wave's K slice ----
  // bfrag[g][kk] holds k-slice (kk+rot)&7 to match rotated A-loads.
  const float* Wg[4] = {W1, W2, W3, W4};
  short8 bfrag[4][8];
#pragma unroll
  for (int g = 0; g < 4; ++g) {
    const float* wrow = Wg[g] + (size_t)(j0 + m) * D + kbase;
#pragma unroll
    for (int kk = 0; kk < 8; ++kk) {
      const int kkr = (kk + rot) & 7;
      float4 fa = *(const float4*)(wrow + kkr * 32 + kg);
      float4 fb = *(const float4*)(wrow + kkr * 32 + kg + 4);
      short8 v;
      v[0] = (short)f2bf(fa.x); v[1] = (short)f2bf(fa.y);
      v[2] = (short)f2bf(fa.z); v[3] = (short)f2bf(fa.w);
      v[4] = (short)f2bf(fb.x); v[5] = (short)f2bf(fb.y);
      v[6] = (short)f2bf(fb.z); v[7] = (short)f2bf(fb.w);
      bfrag[g][kk] = v;
    }
  }

  // producer/gate-math mapping: tid -> (row gb, colpair jp); publish slab of
  // wave wv = rows [8wv,8wv+8) x 16 cols = 256 B contiguous at blk*1024+wv*256.
  const int gb   = tid >> 3;            // 0..31
  const int jp   = (tid & 7) * 2;       // 0,2,..,14
  const int jcol = j0 + jp;

  const float bsum0 = bias[jcol], bsum1 = bias[jcol + 1];
  const float bf0 = b1[jcol] + bsum0, bf1 = b1[jcol + 1] + bsum1;
  const float bi0 = b2[jcol] + bsum0, bi1 = b2[jcol + 1] + bsum1;
  const float bg0 = b3[jcol] + bsum0, bg1 = b3[jcol + 1] + bsum1;
  const float bo0 = b4[jcol] + bsum0, bo1 = b4[jcol + 1] + bsum1;

  // ---- publish s_0 tile slab (wave-autonomous), drain own wave, flags x8 ----
  {
    float2 x0 = *(const float2*)(x + (size_t)gb * T * D + jcol);
    st_u32_llc(sq + blk * 256 + tid,
               (unsigned)f2bf(x0.x) | ((unsigned)f2bf(x0.y) << 16));
    asm volatile("s_waitcnt vmcnt(0)" ::: "memory");
    if (lane < 8) st_u32_llc(flags + lane * 256 + 4 * blk + wv, 1u);
  }

  // A-load base (u16 units): tile (kbase>>4)+(kg>>4), row m, col (kg&8)
  const int aoff = ((kbase >> 4) + (kg >> 4)) * 512 + m * 16 + (kg & 8);

  // consumer poll: 64 producer-wave flags (blocks [16wv,16wv+16) x 4 waves)
  // from replica blk&7 — one coalesced 256 B read.
  const unsigned* pollp = flags + rot * 256 + 64 * wv + lane;

  float c0 = 0.0f, c1 = 0.0f;

  for (int t = 0; t < T; ++t) {
    // x[t+1] prefetch (plain cached; completes under poll/MFMA)
    float xa = 0.0f, xb = 0.0f;
    if (t + 1 < T) {
      float2 xn = *(const float2*)(x + (size_t)gb * T * D + (size_t)(t + 1) * D + jcol);
      xa = xn.x; xb = xn.y;
    }

    // ---- tight poll on replica flag lines ----
    {
      const unsigned tgt = (unsigned)(t + 1);
      int guard = 0;
      for (;;) {
        unsigned f = ld_u32_llc(pollp);
        if (__all((int)(f >= tgt))) break;
        if (++guard > (1 << 22)) break;   // fail loud, never hang
      }
    }
    asm volatile("" ::: "memory");
    __builtin_amdgcn_sched_barrier(0);

    // ---- batched A-loads, K-slice order rotated by blk ----
    const unsigned short* ap =
        (const unsigned short*)sq + (size_t)(t & 1) * 32768 + aoff;
    short8 a0[8], a1[8];
#pragma unroll
    for (int kk = 0; kk < 8; ++kk) {
      const int kkr = (kk + rot) & 7;
      asm volatile("global_load_dwordx4 %0, %1, off sc0 sc1"
                   : "=v"(a0[kk]) : "v"(ap + kkr * 1024));
      asm volatile("global_load_dwordx4 %0, %1, off sc0 sc1"
                   : "=v"(a1[kk]) : "v"(ap + kkr * 1024 + 256));
    }
    asm volatile("s_waitcnt vmcnt(0)" ::: "memory");
    __builtin_amdgcn_sched_barrier(0);

    // ---- z partial: M=32 x N=64 (4 gates x 16) x K=256 ----
    f32x4 acc[2][4];
#pragma unroll
    for (int mt = 0; mt < 2; ++mt)
#pragma unroll
      for (int g = 0; g < 4; ++g) acc[mt][g] = (f32x4){0.f, 0.f, 0.f, 0.f};

#pragma unroll
    for (int kk = 0; kk < 8; ++kk) {
#pragma unroll
      for (int g = 0; g < 4; ++g) {
        acc[0][g] = __builtin_amdgcn_mfma_f32_16x16x32_bf16(a0[kk], bfrag[g][kk], acc[0][g], 0, 0, 0);
        acc[1][g] = __builtin_amdgcn_mfma_f32_16x16x32_bf16(a1[kk], bfrag[g][kk], acc[1][g], 0, 0, 0);
      }
    }

    // ---- exchange partials into parity buffer; ONE barrier per step ----
    const int pz = t & 1;
    {
      const int zr = (lane >> 4) * 4;
#pragma unroll
      for (int g = 0; g < 4; ++g)
#pragma unroll
        for (int r = 0; r < 4; ++r) {
          zx[pz][wv][zr + r][g * 16 + m]      = acc[0][g][r];
          zx[pz][wv][zr + r + 16][g * 16 + m] = acc[1][g][r];
        }
    }
    __syncthreads();

    // ---- reduce 4 K-partials + gate math for (gb, jcol/jcol+1) ----
    float zf0, zf1, zi0, zi1, zg0, zg1, zo0, zo1;
    {
      float2 f_ = *(const float2*)&zx[pz][0][gb][jp];
      float2 i_ = *(const float2*)&zx[pz][0][gb][16 + jp];
      float2 g_ = *(const float2*)&zx[pz][0][gb][32 + jp];
      float2 o_ = *(const float2*)&zx[pz][0][gb][48 + jp];
      zf0 = f_.x; zf1 = f_.y; zi0 = i_.x; zi1 = i_.y;
      zg0 = g_.x; zg1 = g_.y; zo0 = o_.x; zo1 = o_.y;
#pragma unroll
      for (int w = 1; w < 4; ++w) {
        f_ = *(const float2*)&zx[pz][w][gb][jp];
        i_ = *(const float2*)&zx[pz][w][gb][16 + jp];
        g_ = *(const float2*)&zx[pz][w][gb][32 + jp];
        o_ = *(const float2*)&zx[pz][w][gb][48 + jp];
        zf0 += f_.x; zf1 += f_.y; zi0 += i_.x; zi1 += i_.y;
        zg0 += g_.x; zg1 += g_.y; zo0 += o_.x; zo1 += o_.y;
      }
    }

    float f0 = sigm(zf0 + bf0), f1 = sigm(zf1 + bf1);
    float i0 = sigm(zi0 + bi0) * tanh_fast(zg0 + bg0);
    float i1 = sigm(zi1 + bi1) * tanh_fast(zg1 + bg1);
    c0 = c0 * f0 + i0;
    c1 = c1 * f1 + i1;
    float h0 = sigm(zo0 + bo0) * tanh_fast(c0);
    float h1 = sigm(zo1 + bo1) * tanh_fast(c1);

    if (t + 1 < T) {
      // wave-autonomous publish: 256 B slab, drain own wave, flags x8
      unsigned* snq = sq + (size_t)((t + 1) & 1) * 16384 + blk * 256;
      st_u32_llc(snq + tid,
                 (unsigned)f2bf(h0 + xa) | ((unsigned)f2bf(h1 + xb) << 16));
      asm volatile("s_waitcnt vmcnt(0)" ::: "memory");
      if (lane < 8) st_u32_llc(flags + lane * 256 + 4 * blk + wv, (unsigned)(t + 2));
      // out store off the critical path (plain cached)
      *(float2*)(out + (size_t)gb * T * D + (size_t)t * D + jcol) = make_float2(h0, h1);
    } else {
      *(float2*)(out + (size_t)gb * T * D + (size_t)t * D + jcol) = make_float2(h0, h1);
      float* cT = out + (size_t)B * T * D;
      float* hT = cT + (size_t)B * D;
      *(float2*)(cT + (size_t)gb * D + jcol) = make_float2(c0, c1);
      *(float2*)(hT + (size_t)gb * D + jcol) = make_float2(h0, h1);
    }
  }
}

extern "C" void kernel_launch(void* const* d_in, const int* in_sizes, int n_in,
                              void* d_out, int out_size, void* d_ws, size_t ws_size,
                              hipStream_t stream) {
  const float* x    = (const float*)d_in[0];
  const float* W1   = (const float*)d_in[1];
  const float* b1   = (const float*)d_in[2];
  const float* W2   = (const float*)d_in[3];
  const float* b2   = (const float*)d_in[4];
  const float* W3   = (const float*)d_in[5];
  const float* b3   = (const float*)d_in[6];
  const float* W4   = (const float*)d_in[7];
  const float* b4   = (const float*)d_in[8];
  const float* bias = (const float*)d_in[9];

  unsigned* flags = (unsigned*)d_ws;                    // 8 replicas x 1 KB
  unsigned* sq    = (unsigned*)((char*)d_ws + 8192);    // [2][64][256] u32 = 128 KB

  hipMemsetAsync(d_ws, 0, 8192, stream);  // reset all flag replicas (replay-safe)
  hipLaunchKernelGGL(lstm_persistent, dim3(NBLK), dim3(NTHR), 0, stream,
                     x, W1, b1, W2, b2, W3, b3, W4, b4, bias,
                     (float*)d_out, flags, sq);
}